// Round 4
// baseline (1380.111 us; speedup 1.0000x reference)
//
#include <hip/hip_runtime.h>

// Neighbor search: M=N=12288, DIM=3.
// d_out layout (float32, flat):
//   [0 .. M]                row_splits
//   [M+1 .. M+1+M*N)        mask (0.0 / 1.0)
//   [M+1+M*N .. +2*M*N)     weights (d2 if mask else 0)
//
// R5 theory: three store-instruction structures (scalar / aligned f4 /
// aligned nt f4) all give nbr ~460us vs the 193us pure-write floor the
// poison fill itself demonstrates (775us for 4.83GB = 6.25 TB/s). The
// invariant across them is GLOBAL WRITE ORDER: thousands of interleaved
// per-block streams over a ~75MB active region -> dirty-L2 evictions reach
// DRAM in scrambled order -> row-buffer thrash (~2.6 TB/s). The fill writes
// one sequential front. Fix: sweep-front mapping. Block b owns column
// window w=b%12 (1024 cols; data fragment hoisted to registers, LDS read
// once) and walks rows m = t*128 + b/12. At step t, the 1536 resident
// blocks collectively write rows [128t,128(t+1)) = one contiguous 6.3MB
// band per plane, sweeping the output sequentially like the fill does.
// Plain dword stores (L2 merges lines); no nt (evict-early would flush
// partial lines).
//
// Bit-exactness vs numpy/BLAS fp32 (unchanged):
//   sq = (x0*x0 + x1*x1) + x2*x2
//   dot = fma(q2,d2, fma(q1,d1, q0*d0))
//   d2  = (sq_q + sq_d) - 2*dot ; max(d2,0) ; mask = d2 <= r*r
// counts are integer sums (order-independent, exact).

#define BLK 256
#define COLW 1024   // columns per window; N % COLW == 0 (12288/1024 = 12)
#define MAXITERS 128

__global__ __launch_bounds__(BLK) void zero_counts(int* __restrict__ counts,
                                                   int M) {
    const int i = blockIdx.x * BLK + threadIdx.x;
    if (i < M) counts[i] = 0;
}

__global__ __launch_bounds__(BLK) void nbr_kernel(
    const float* __restrict__ data,
    const float* __restrict__ queries,
    const float* __restrict__ radius_p,
    float* __restrict__ out,
    int* __restrict__ counts,
    int N, int WINDOWS, int RGR, int ITERS,
    long long mask_off, long long w_off)
{
    __shared__ float tile[COLW * 3];
    __shared__ int rowcnt[MAXITERS];

    const int tid = threadIdx.x;
    const int w  = blockIdx.x % WINDOWS;   // column window
    const int rg = blockIdx.x / WINDOWS;   // row offset within each band
    const long long colbase = (long long)w * COLW;

    // Stage this block's data window once (12 KB), coalesced float4.
    {
        const float4* src =
            reinterpret_cast<const float4*>(data + 3 * colbase);
        float4* dst = reinterpret_cast<float4*>(tile);
#pragma unroll
        for (int i = 0; i < COLW * 3 / 4 / BLK; ++i)  // 3 iters
            dst[i * BLK + tid] = src[i * BLK + tid];
    }
    for (int i = tid; i < ITERS; i += BLK) rowcnt[i] = 0;
    __syncthreads();

    // Per-thread column group: cols colbase + 4*tid + j, j=0..3.
    // LDS words 12*tid .. 12*tid+11 -> 3 aligned b128 reads, loop-invariant:
    // hoisted to registers for the whole row sweep.
    const float4 A = reinterpret_cast<const float4*>(tile)[3 * tid + 0];
    const float4 B = reinterpret_cast<const float4*>(tile)[3 * tid + 1];
    const float4 C = reinterpret_cast<const float4*>(tile)[3 * tid + 2];
    // xyz interleave: x0 y0 z0 x1 | y1 z1 x2 y2 | z2 x3 y3 z3
    const float d0[4]  = {A.x, A.w, B.z, C.y};
    const float d1[4]  = {A.y, B.x, B.w, C.z};
    const float d2e[4] = {A.z, B.y, C.x, C.w};
    float sqd[4];
#pragma unroll
    for (int j = 0; j < 4; ++j)
        sqd[j] = __fadd_rn(
            __fadd_rn(__fmul_rn(d0[j], d0[j]), __fmul_rn(d1[j], d1[j])),
            __fmul_rn(d2e[j], d2e[j]));

    const float r = radius_p[0];
    const float r2 = __fmul_rn(r, r);

    const long long c0 = colbase + 4 * tid;  // this thread's first column

    for (int t = 0; t < ITERS; ++t) {
        const int m = t * RGR + rg;          // all blocks: same row band at t
        const float q0 = queries[3 * m + 0]; // block-uniform -> s_load
        const float q1 = queries[3 * m + 1];
        const float q2 = queries[3 * m + 2];
        const float sqq = __fadd_rn(
            __fadd_rn(__fmul_rn(q0, q0), __fmul_rn(q1, q1)),
            __fmul_rn(q2, q2));

        float* mrow = out + mask_off + (long long)m * N + c0;
        float* wrow = out + w_off    + (long long)m * N + c0;

        int cc = 0;
#pragma unroll
        for (int j = 0; j < 4; ++j) {
            const float dot = __fmaf_rn(q2, d2e[j],
                                __fmaf_rn(q1, d1[j], __fmul_rn(q0, d0[j])));
            float v = __fsub_rn(__fadd_rn(sqq, sqd[j]),
                                __fmul_rn(2.0f, dot));
            v = fmaxf(v, 0.0f);
            const bool in = (v <= r2);
            mrow[j] = in ? 1.0f : 0.0f;   // wave: 1KB contiguous run
            wrow[j] = in ? v : 0.0f;
            cc += in ? 1 : 0;
        }
        // Per-row count: wave shuffle reduce, one LDS atomic per wave.
        for (int off = 32; off > 0; off >>= 1) cc += __shfl_down(cc, off);
        if ((tid & 63) == 0) atomicAdd(&rowcnt[t], cc);
    }

    __syncthreads();
    // One device atomic per (block, row): 12 partials per row total.
    for (int t = tid; t < ITERS; t += BLK)
        atomicAdd(&counts[t * RGR + rg], rowcnt[t]);
}

// Single-block exclusive scan of counts[M] -> row_splits[M+1] (as floats).
__global__ __launch_bounds__(256) void scan_kernel(
    const int* __restrict__ counts, float* __restrict__ out, int M)
{
    __shared__ int sums[256];
    const int t = threadIdx.x;
    const int CH = (M + 255) / 256;  // 48 for M=12288
    const int base = t * CH;

    int local[64];  // CH <= 64 assumed
    int s = 0;
    for (int i = 0; i < CH; ++i) {
        const int v = (base + i < M) ? counts[base + i] : 0;
        local[i] = v;
        s += v;
    }
    sums[t] = s;
    __syncthreads();
    for (int off = 1; off < 256; off <<= 1) {
        const int v = (t >= off) ? sums[t - off] : 0;
        __syncthreads();
        sums[t] += v;
        __syncthreads();
    }
    int prefix = sums[t] - s;  // exclusive prefix of this thread's chunk
    for (int i = 0; i < CH; ++i) {
        if (base + i < M) out[base + i] = (float)prefix;
        prefix += local[i];
    }
    if (t == 255) out[M] = (float)prefix;  // total
}

extern "C" void kernel_launch(void* const* d_in, const int* in_sizes, int n_in,
                              void* d_out, int out_size, void* d_ws, size_t ws_size,
                              hipStream_t stream) {
    const float* data    = (const float*)d_in[0];
    const float* queries = (const float*)d_in[1];
    const float* radius  = (const float*)d_in[2];

    const int N = in_sizes[0] / 3;  // 12288
    const int M = in_sizes[1] / 3;  // 12288

    float* out = (float*)d_out;
    int* counts = (int*)d_ws;       // M ints

    const long long mask_off = (long long)M + 1;
    const long long w_off = mask_off + (long long)M * N;

    const int WINDOWS = N / COLW;   // 12 (requires N % COLW == 0)
    // Rows per band: grid = WINDOWS * RGR; pick RGR so M % RGR == 0 and
    // ITERS = M / RGR <= MAXITERS. For M = 12288: RGR = 128, ITERS = 96,
    // grid = 1536 = 6 blocks/CU x 256 CU (all resident -> coherent sweep).
    int RGR = 128;
    while ((M % RGR) != 0 || (M / RGR) > MAXITERS) RGR <<= 1;
    const int ITERS = M / RGR;

    zero_counts<<<(M + BLK - 1) / BLK, BLK, 0, stream>>>(counts, M);
    nbr_kernel<<<WINDOWS * RGR, BLK, 0, stream>>>(
        data, queries, radius, out, counts, N, WINDOWS, RGR, ITERS,
        mask_off, w_off);
    scan_kernel<<<1, 256, 0, stream>>>(counts, out, M);
}